// Round 5
// baseline (96.757 us; speedup 1.0000x reference)
//
#include <hip/hip_runtime.h>
#include <cstdint>

// ---------------------------------------------------------------------------
// H3 block: out = q * S4D( v * Shift(k) ),  q/k/v = W{q,k,v} @ x + b
// GEMM: merged M=1536 x N=16384 x K=512. 256x256 tile, 8 waves (2M x 4N),
//   BK=32, TRIPLE-buffered LDS (96 KB), counted s_waitcnt vmcnt(4) (never 0
//   in main loop), raw s_barrier, setprio around MFMA clusters,
//   global_load_lds(16B) w/ inverse-swizzled source, swizzled ds_read_b128.
// S4D + Shift as per-(b,h) chunked MFMA GEMMs (T=64) vs per-h tables stored
//   in pre-swizzled LDS-image layout. Swizzle: 16B slot s -> s ^ key(row).
// ---------------------------------------------------------------------------

#define DMODEL 512
#define LSEQ 2048

typedef _Float16 half_t;
typedef __attribute__((ext_vector_type(4))) _Float16 half4v;
typedef __attribute__((ext_vector_type(8))) _Float16 half8v;
typedef __attribute__((ext_vector_type(4))) float floatx4;

#define SW(R, c) ((R) * 64 + ((((c) >> 3) ^ ((R) & 7)) << 3) + ((c) & 7))

__device__ __forceinline__ void gload_lds16(const half_t* g, half_t* l) {
  __builtin_amdgcn_global_load_lds(
      (const __attribute__((address_space(1))) uint32_t*)g,
      (__attribute__((address_space(3))) uint32_t*)l, 16, 0, 0);
}

// ---------------- convert W (3 x 512x512) fp32 -> f16 ----------------------
__global__ __launch_bounds__(256) void convert_w(
    const float* __restrict__ Wq, const float* __restrict__ Wk,
    const float* __restrict__ Wv, half_t* __restrict__ W16) {
  int i = blockIdx.x * 256 + threadIdx.x;
  const float* src = (i < 262144) ? Wq : ((i < 524288) ? Wk : Wv);
  int j = i & 262143;
  W16[i] = (half_t)src[j];
}

// ---------------- transpose x (B,D,L) f32 -> xT (B,L,D) f16 ----------------
__global__ __launch_bounds__(256) void transpose_x(
    const float* __restrict__ x, half_t* __restrict__ xT) {
  __shared__ float tile[32][33];
  int b = blockIdx.z;
  int d0 = blockIdx.y * 32;
  int l0 = blockIdx.x * 32;
  int tx = threadIdx.x, ty = threadIdx.y;       // 32 x 8
  const float* xp = x + (size_t)b * DMODEL * LSEQ;
#pragma unroll
  for (int k = 0; k < 4; k++)
    tile[ty + 8 * k][tx] = xp[(size_t)(d0 + ty + 8 * k) * LSEQ + l0 + tx];
  __syncthreads();
  half_t* op = xT + (size_t)b * LSEQ * DMODEL;
#pragma unroll
  for (int k = 0; k < 4; k++)
    op[(size_t)(l0 + ty + 8 * k) * DMODEL + d0 + tx] = (half_t)tile[tx][ty + 8 * k];
}

// ---------------- per-h table builder (setup folded in) --------------------
__global__ __launch_bounds__(256) void s4d_tables(
    const float* __restrict__ log_dt, const float* __restrict__ A_real,
    const float* __restrict__ A_imag, const float* __restrict__ C_re,
    const float* __restrict__ C_im, const float* __restrict__ shC,
    half_t* __restrict__ Vt, half_t* __restrict__ Et, half_t* __restrict__ Tt,
    half_t* __restrict__ T1t, half_t* __restrict__ T2t,
    float* __restrict__ wt2) {
  __shared__ float aL[32], bL[32], wrL[32], wiL[32], crL[32], ciL[32];
  __shared__ float Kt[64], tapl[64];
  int h = blockIdx.x;
  int tid = threadIdx.x;
  if (tid < 64) { Kt[tid] = 0.f; tapl[tid] = shC[h * 64 + tid]; }
  if (tid < 32) {
    int n = tid, hn = h * 32 + n;
    float dt = expf(log_dt[h]);
    float Ar = -expf(A_real[hn]), Ai = A_imag[hn];
    float a = dt * Ar, b = dt * Ai;
    float ea = expf(a);
    float wr = ea * cosf(b), wi = ea * sinf(b);
    float Am2 = Ar * Ar + Ai * Ai;
    float zr = wr - 1.0f, zi = wi;
    float qr = (zr * Ar + zi * Ai) / Am2;
    float qi = (zi * Ar - zr * Ai) / Am2;
    aL[n] = a; bL[n] = b; wrL[n] = wr; wiL[n] = wi;
    crL[n] = C_re[hn] * qr - C_im[hn] * qi;
    ciL[n] = C_re[hn] * qi + C_im[hn] * qr;
    float e64 = expf(64.0f * a);
    wt2[h * 64 + 2 * n]     = e64 * cosf(64.0f * b);
    wt2[h * 64 + 2 * n + 1] = e64 * sinf(64.0f * b);
  }
  __syncthreads();
  size_t base = (size_t)h * 4096;
  {
    int r = tid >> 2;
    int nb = (tid & 3) * 8;
    float ksum = 0.f;
#pragma unroll
    for (int i = 0; i < 8; i++) {
      int n = nb + i;
      float a = aL[n], b = bL[n];
      float cr = crL[n], ci = ciL[n];
      float er = expf(a * (float)r);
      float w0r = er * cosf(b * (float)r), w0i = er * sinf(b * (float)r);
      ksum += 2.f * (cr * w0r - ci * w0i);
      float wr = wrL[n], wi = wiL[n];
      float w1r = w0r * wr - w0i * wi, w1i = w0r * wi + w0i * wr;
      Et[base + SW(r, 2 * n)]     = (half_t)(2.f * (cr * w1r - ci * w1i));
      Et[base + SW(r, 2 * n + 1)] = (half_t)(-2.f * (cr * w1i + ci * w1r));
      Vt[base + SW(2 * n, 63 - r)]     = (half_t)w0r;
      Vt[base + SW(2 * n + 1, 63 - r)] = (half_t)w0i;
    }
    atomicAdd(&Kt[r], ksum);
  }
  __syncthreads();
#pragma unroll
  for (int e = 0; e < 16; e++) {
    int idx = e * 256 + tid;
    int r = idx >> 6, t = idx & 63;
    int d = r - t;
    size_t a = base + SW(r, t);
    Tt[a]  = (d >= 0) ? (half_t)Kt[d] : (half_t)0.f;
    T1t[a] = (d >= 0) ? (half_t)tapl[d] : (half_t)0.f;
    T2t[a] = (d < 0) ? (half_t)tapl[64 + d] : (half_t)0.f;
  }
}

// ---------------- merged qkv GEMM (256x256, 8 waves, counted vmcnt) --------
__global__ __launch_bounds__(512, 2) void gemm_qkv(
    const half_t* __restrict__ xT, const half_t* __restrict__ Wstk,
    const float* __restrict__ bq, const float* __restrict__ bk,
    const float* __restrict__ bv, half_t* __restrict__ outq,
    half_t* __restrict__ outk, half_t* __restrict__ outv) {
  extern __shared__ half_t smem[];
  half_t* ldsA = smem;            // 3 bufs x 8192 halfs (256 rows x 32)
  half_t* ldsB = smem + 24576;    // 3 bufs x 8192 halfs
  int flat = blockIdx.x;                        // 384 = 8 xcd x 48
  int swz = (flat & 7) * 48 + (flat >> 3);      // bijective XCD swizzle
  int nt = swz / 6, mt = swz - nt * 6;
  int n0 = nt * 256, m0 = mt * 256;
  int tid = threadIdx.x;
  int lane = tid & 63, wid = tid >> 6;
  int wm = wid >> 2, wn = wid & 3;              // 2M x 4N wave grid
  int lrow = lane & 15, lg = lane >> 4;
  int r_in = tid >> 2;                          // staging row 0..127
  int s_in = (tid & 3) ^ ((r_in >> 1) & 3);     // inverse-swizzled src slot

  const half_t* gA = Wstk + (size_t)(m0 + r_in) * 512 + s_in * 8;
  const half_t* gB = xT + (size_t)(n0 + r_in) * 512 + s_in * 8;
  int dst = tid * 8;                            // linear LDS dest (halfs)

  floatx4 acc[8][4];
#pragma unroll
  for (int i = 0; i < 8; i++)
#pragma unroll
    for (int j = 0; j < 4; j++) acc[i][j] = (floatx4){0.f, 0.f, 0.f, 0.f};

#define STAGE(buf, kt, ih)                                                   \
  do {                                                                       \
    gload_lds16(gA + (size_t)(ih)*65536 + (kt)*32,                           \
                ldsA + (buf)*8192 + (ih)*4096 + dst);                        \
    gload_lds16(gB + (size_t)(ih)*65536 + (kt)*32,                           \
                ldsB + (buf)*8192 + (ih)*4096 + dst);                        \
  } while (0)

  // prologue: tiles 0 and 1 in flight; wait tile 0 (4 of tile 1 may fly)
  STAGE(0, 0, 0); STAGE(0, 0, 1);
  STAGE(1, 1, 0); STAGE(1, 1, 1);
  asm volatile("s_waitcnt vmcnt(4)" ::: "memory");
  __builtin_amdgcn_s_barrier();

  int cur = 0, stb = 2;
  for (int t = 0; t < 16; t++) {
    const half_t* Ac = ldsA + cur * 8192;
    const half_t* Bc = ldsB + cur * 8192;
    half8v af[4], bf[4];
    // ---- phase 0: A-half 0 + all B frags; stage half 0 of tile t+2 ----
#pragma unroll
    for (int i = 0; i < 4; i++) {
      int ra = wm * 128 + i * 16 + lrow;
      af[i] = *(const half8v*)(Ac + ra * 32 + ((lg ^ ((ra >> 1) & 3)) << 3));
    }
#pragma unroll
    for (int j = 0; j < 4; j++) {
      int rb = wn * 64 + j * 16 + lrow;
      bf[j] = *(const half8v*)(Bc + rb * 32 + ((lg ^ ((rb >> 1) & 3)) << 3));
    }
    if (t < 14) STAGE(stb, t + 2, 0);
    __builtin_amdgcn_s_setprio(1);
#pragma unroll
    for (int i = 0; i < 4; i++)
#pragma unroll
      for (int j = 0; j < 4; j++)
        acc[i][j] = __builtin_amdgcn_mfma_f32_16x16x32_f16(af[i], bf[j],
                                                           acc[i][j], 0, 0, 0);
    __builtin_amdgcn_s_setprio(0);
    __builtin_amdgcn_s_barrier();
    // ---- phase 1: A-half 1 (B frags held in regs); stage half 1 ----
#pragma unroll
    for (int i = 0; i < 4; i++) {
      int ra = wm * 128 + 64 + i * 16 + lrow;
      af[i] = *(const half8v*)(Ac + ra * 32 + ((lg ^ ((ra >> 1) & 3)) << 3));
    }
    if (t < 14) STAGE(stb, t + 2, 1);
    __builtin_amdgcn_s_setprio(1);
#pragma unroll
    for (int i = 0; i < 4; i++)
#pragma unroll
      for (int j = 0; j < 4; j++)
        acc[4 + i][j] = __builtin_amdgcn_mfma_f32_16x16x32_f16(af[i], bf[j],
                                                               acc[4 + i][j],
                                                               0, 0, 0);
    __builtin_amdgcn_s_setprio(0);
    // counted wait: next tile's issues (oldest) done; t+2's 4 may stay in flight
    if (t < 14) asm volatile("s_waitcnt vmcnt(4)" ::: "memory");
    else        asm volatile("s_waitcnt vmcnt(0)" ::: "memory");
    __builtin_amdgcn_s_barrier();
    cur = (cur == 2) ? 0 : cur + 1;
    stb = (stb == 2) ? 0 : stb + 1;
  }
#undef STAGE

  // epilogue: D col = lane&15 (n), row = 4*(lane>>4)+reg (m). z uniform/block.
  int z = m0 >> 9;
  const float* bias = (z == 0) ? bq : ((z == 1) ? bk : bv);
  half_t* outp = (z == 0) ? outq : ((z == 1) ? outk : outv);
#pragma unroll
  for (int i = 0; i < 8; i++) {
    int d = (m0 + wm * 128 + i * 16 + 4 * lg) & 511;
#pragma unroll
    for (int j = 0; j < 4; j++) {
      int n = n0 + wn * 64 + j * 16 + lrow;
      int b = n >> 11, l = n & 2047;
#pragma unroll
      for (int reg = 0; reg < 4; reg++) {
        float val = acc[i][j][reg] + bias[d + reg];
        size_t bhbase = ((size_t)(b * 512 + d + reg)) * 2048;
        if (z == 0) {
          outp[bhbase + l] = (half_t)val;        // q: linear (b,h,l)
        } else {                                  // k,v: swizzled LDS image
          int jj = l >> 6, c = l & 63;
          outp[bhbase + SW(jj, c)] = (half_t)val;
        }
      }
    }
  }
}

// ---------------- fused Shift + S4D + final q-multiply ---------------------
// One block per (b,h); wave w: mi = w&1 (chunk-tile), ri in {w>>1, w>>1+2}.
__global__ __launch_bounds__(256) void s4d_main(
    const half_t* __restrict__ kimg, const half_t* __restrict__ vimg,
    const half_t* __restrict__ T1t, const half_t* __restrict__ T2t,
    const half_t* __restrict__ Vt, const half_t* __restrict__ Et,
    const half_t* __restrict__ Tt, const float* __restrict__ wt2,
    const float* __restrict__ shD, const float* __restrict__ s4D,
    const half_t* __restrict__ qbuf, float* __restrict__ outp) {
  __shared__ half_t kl[33 * 64];   // row 0 zeros; row 1+j = k chunk j
  __shared__ half_t vg[32 * 64];   // v, later G~ (f16)
  __shared__ half_t uh[32 * 64];   // u = v * shift(k)
  __shared__ half_t tab0[64 * 64]; // T1 -> E
  __shared__ half_t tab1[64 * 64]; // T2 -> T
  __shared__ half_t tab2[64 * 64]; // V
  __shared__ float SG[32 * 66];
  int bh = blockIdx.x;
  int h = bh & 511;
  int tid = threadIdx.x;
  int lane = tid & 63, wid = tid >> 6;
  int lrow = lane & 15, lg = lane >> 4;
  int mi = wid & 1;
  int ri0 = wid >> 1;

  // ---- stage k, v, T1, T2, V via gload_lds (8 per wave) ----
  {
    const half_t* kp = kimg + (size_t)bh * 2048;
    const half_t* vp = vimg + (size_t)bh * 2048;
    size_t tb = (size_t)h * 4096;
    gload_lds16(kp + wid * 512 + lane * 8, kl + 64 + wid * 512);
    gload_lds16(vp + wid * 512 + lane * 8, vg + wid * 512);
#pragma unroll
    for (int i = 0; i < 2; i++) {
      int c = wid * 2 + i;
      gload_lds16(T1t + tb + c * 512 + lane * 8, tab0 + c * 512);
      gload_lds16(T2t + tb + c * 512 + lane * 8, tab1 + c * 512);
      gload_lds16(Vt + tb + c * 512 + lane * 8, tab2 + c * 512);
    }
  }
  if (tid < 8) {
    half8v zz = {(_Float16)0, (_Float16)0, (_Float16)0, (_Float16)0,
                 (_Float16)0, (_Float16)0, (_Float16)0, (_Float16)0};
    *(half8v*)(kl + tid * 8) = zz;
  }
  float sDsh = shD[h];
  float sD4 = s4D[h];
  __syncthreads();

#define LDF(base, r, ks, key) \
  (*(const half8v*)((base) + (r) * 64 + (((ks) * 4 + lg) ^ (key)) * 8))

  floatx4 acc[2];
  // ---- shift: shift[j][r] = k_j @ T1' + k_{j-1} @ T2' ----
  acc[0] = (floatx4){0.f, 0.f, 0.f, 0.f};
  acc[1] = (floatx4){0.f, 0.f, 0.f, 0.f};
  {
    int jA = mi * 16 + lrow;
    int key1 = lrow & 7, key2 = (lrow + 7) & 7;
#pragma unroll
    for (int ks = 0; ks < 2; ks++) {
      half8v a1 = LDF(kl, 1 + jA, ks, key1);
      half8v a2 = LDF(kl, jA, ks, key2);
#pragma unroll
      for (int tt = 0; tt < 2; tt++) {
        int rb = (ri0 + tt * 2) * 16 + lrow;
        half8v b1 = LDF(tab0, rb, ks, lrow & 7);
        half8v b2 = LDF(tab1, rb, ks, lrow & 7);
        acc[tt] = __builtin_amdgcn_mfma_f32_16x16x32_f16(a1, b1, acc[tt], 0, 0, 0);
        acc[tt] = __builtin_amdgcn_mfma_f32_16x16x32_f16(a2, b2, acc[tt], 0, 0, 0);
      }
    }
  }
  // u = v * (shift + shD*k)
#pragma unroll
  for (int tt = 0; tt < 2; tt++) {
#pragma unroll
    for (int reg = 0; reg < 4; reg++) {
      int j = mi * 16 + 4 * lg + reg;
      int r = (ri0 + tt * 2) * 16 + lrow;
      int cph = (((r >> 3) ^ (j & 7)) << 3) + (r & 7);
      float kvv = (float)kl[(1 + j) * 64 + cph];
      float vvv = (float)vg[j * 64 + cph];
      uh[j * 64 + cph] = (half_t)(vvv * (acc[tt][reg] + sDsh * kvv));
    }
  }
  __syncthreads();

  // ---- issue E,T stage (overlaps with S phase) ----
  {
    size_t tb = (size_t)h * 4096;
#pragma unroll
    for (int i = 0; i < 2; i++) {
      int c = wid * 2 + i;
      gload_lds16(Et + tb + c * 512 + lane * 8, tab0 + c * 512);
      gload_lds16(Tt + tb + c * 512 + lane * 8, tab1 + c * 512);
    }
  }

  // ---- S phase: S[j][m] = u_j @ V' ----
  acc[0] = (floatx4){0.f, 0.f, 0.f, 0.f};
  acc[1] = (floatx4){0.f, 0.f, 0.f, 0.f};
#pragma unroll
  for (int ks = 0; ks < 2; ks++) {
    half8v a = LDF(uh, mi * 16 + lrow, ks, lrow & 7);
#pragma unroll
    for (int tt = 0; tt < 2; tt++) {
      int rb = (ri0 + tt * 2) * 16 + lrow;
      half8v b = LDF(tab2, rb, ks, lrow & 7);
      acc[tt] = __builtin_amdgcn_mfma_f32_16x16x32_f16(a, b, acc[tt], 0, 0, 0);
    }
  }
#pragma unroll
  for (int tt = 0; tt < 2; tt++) {
    int ri = ri0 + tt * 2;
#pragma unroll
    for (int reg = 0; reg < 4; reg++) {
      int j = mi * 16 + 4 * lg + reg;
      SG[j * 66 + ri * 16 + lrow] = acc[tt][reg];
    }
  }
  __syncthreads();   // drains E,T stage too

  // ---- scan over chunks (thread n), SG[j] <- G_{j-1} ----
  if (tid < 32) {
    int n = tid;
    float wTr = wt2[h * 64 + 2 * n], wTi = wt2[h * 64 + 2 * n + 1];
    float gr = 0.f, gi = 0.f;
    for (int j = 0; j < 32; j++) {
      float tr = SG[j * 66 + 2 * n], ti = SG[j * 66 + 2 * n + 1];
      SG[j * 66 + 2 * n] = gr; SG[j * 66 + 2 * n + 1] = gi;
      float nr = wTr * gr - wTi * gi + tr;
      gi = wTr * gi + wTi * gr + ti;
      gr = nr;
    }
  }
  __syncthreads();

  // ---- convert G (f32) -> f16 into vg (swizzled) ----
  {
    int j = tid >> 3, s = tid & 7;
    half8v g;
#pragma unroll
    for (int i = 0; i < 8; i++) g[i] = (half_t)SG[j * 66 + s * 8 + i];
    *(half8v*)(vg + j * 64 + (s ^ (j & 7)) * 8) = g;
  }
  __syncthreads();

  // ---- Y: Y[j][r] = G~_j @ E' + u_j @ T' ; out = q*(Y + sD*u) ----
  acc[0] = (floatx4){0.f, 0.f, 0.f, 0.f};
  acc[1] = (floatx4){0.f, 0.f, 0.f, 0.f};
#pragma unroll
  for (int ks = 0; ks < 2; ks++) {
    half8v ag = LDF(vg, mi * 16 + lrow, ks, lrow & 7);
    half8v au = LDF(uh, mi * 16 + lrow, ks, lrow & 7);
#pragma unroll
    for (int tt = 0; tt < 2; tt++) {
      int rb = (ri0 + tt * 2) * 16 + lrow;
      half8v be = LDF(tab0, rb, ks, lrow & 7);
      half8v bt = LDF(tab1, rb, ks, lrow & 7);
      acc[tt] = __builtin_amdgcn_mfma_f32_16x16x32_f16(ag, be, acc[tt], 0, 0, 0);
      acc[tt] = __builtin_amdgcn_mfma_f32_16x16x32_f16(au, bt, acc[tt], 0, 0, 0);
    }
  }
  const half_t* qp = qbuf + (size_t)bh * 2048;
  float* op = outp + (size_t)bh * 2048;
#pragma unroll
  for (int tt = 0; tt < 2; tt++) {
#pragma unroll
    for (int reg = 0; reg < 4; reg++) {
      int j = mi * 16 + 4 * lg + reg;
      int r = (ri0 + tt * 2) * 16 + lrow;
      int cph = (((r >> 3) ^ (j & 7)) << 3) + (r & 7);
      float y = acc[tt][reg] + sD4 * (float)uh[j * 64 + cph];
      int l = j * 64 + r;
      op[l] = (float)qp[l] * y;
    }
  }
#undef LDF
}

// ---------------------------------------------------------------------------
extern "C" void kernel_launch(void* const* d_in, const int* in_sizes, int n_in,
                              void* d_out, int out_size, void* d_ws, size_t ws_size,
                              hipStream_t stream) {
  const float* x      = (const float*)d_in[0];
  const float* Wq     = (const float*)d_in[1];
  const float* bq     = (const float*)d_in[2];
  const float* Wk     = (const float*)d_in[3];
  const float* bk     = (const float*)d_in[4];
  const float* Wv     = (const float*)d_in[5];
  const float* bv     = (const float*)d_in[6];
  const float* shC    = (const float*)d_in[7];
  const float* shD    = (const float*)d_in[8];
  const float* log_dt = (const float*)d_in[9];
  const float* A_real = (const float*)d_in[10];
  const float* A_imag = (const float*)d_in[11];
  const float* C_re   = (const float*)d_in[12];
  const float* C_im   = (const float*)d_in[13];
  const float* s4D    = (const float*)d_in[14];
  float* out = (float*)d_out;
  half_t* wsh = (half_t*)d_ws;

  half_t* qbuf = wsh;                         // 8388608 halfs (linear)
  half_t* kbuf = wsh + 8388608;               // 8388608 (swizzled image)
  half_t* vbuf = wsh + 16777216;              // 8388608 (swizzled image)
  half_t* xT16 = wsh + 25165824;              // 8388608
  half_t* W16  = wsh + 33554432;              // 786432
  half_t* Vt   = wsh + 34340864;              // 2097152 (swizzled image)
  half_t* Et   = wsh + 36438016;              // 2097152
  half_t* Tt   = wsh + 38535168;              // 2097152
  half_t* T1t  = wsh + 40632320;              // 2097152
  half_t* T2t  = wsh + 42729472;              // 2097152
  float*  wt2  = (float*)(wsh + 44826624);    // 32768 f32

  hipFuncSetAttribute((const void*)gemm_qkv,
                      hipFuncAttributeMaxDynamicSharedMemorySize, 98304);

  convert_w<<<3072, 256, 0, stream>>>(Wq, Wk, Wv, W16);
  transpose_x<<<dim3(64, 16, 8), dim3(32, 8), 0, stream>>>(x, xT16);
  s4d_tables<<<512, 256, 0, stream>>>(log_dt, A_real, A_imag, C_re, C_im, shC,
                                      Vt, Et, Tt, T1t, T2t, wt2);
  gemm_qkv<<<dim3(384), 512, 98304, stream>>>(xT16, W16, bq, bk, bv,
                                              qbuf, kbuf, vbuf);
  s4d_main<<<4096, 256, 0, stream>>>(kbuf, vbuf, T1t, T2t, Vt, Et, Tt,
                                     wt2, shD, s4D, qbuf, out);
}

// Round 6
// 95.850 us; speedup vs baseline: 1.0095x; 1.0095x over previous
//
#include <hip/hip_runtime.h>
#include <cstdint>

// ---------------------------------------------------------------------------
// H3 block: out = q * S4D( v * Shift(k) ),  q/k/v = W{q,k,v} @ x + b
// GEMM: merged M=1536 x N=16384 x K=512, 128x128 tile, BK=64, 4 waves,
//   global_load_lds(16B) w/ inverse-swizzled source, swizzled ds_read_b128,
//   mfma_f32_16x16x32_f16, epilogue through LDS -> coalesced half8 stores.
// S4D + Shift as per-(b,h) chunked MFMA GEMMs (T=64) vs per-h tables stored
//   in pre-swizzled LDS-image layout. Swizzle: 16B slot s -> s ^ key(row).
// ---------------------------------------------------------------------------

#define DMODEL 512
#define LSEQ 2048

typedef _Float16 half_t;
typedef __attribute__((ext_vector_type(4))) _Float16 half4v;
typedef __attribute__((ext_vector_type(8))) _Float16 half8v;
typedef __attribute__((ext_vector_type(4))) float floatx4;

#define SW(R, c) ((R) * 64 + ((((c) >> 3) ^ ((R) & 7)) << 3) + ((c) & 7))

__device__ __forceinline__ void gload_lds16(const half_t* g, half_t* l) {
  __builtin_amdgcn_global_load_lds(
      (const __attribute__((address_space(1))) uint32_t*)g,
      (__attribute__((address_space(3))) uint32_t*)l, 16, 0, 0);
}

// ---------------- convert W (3 x 512x512) fp32 -> f16 ----------------------
__global__ __launch_bounds__(256) void convert_w(
    const float* __restrict__ Wq, const float* __restrict__ Wk,
    const float* __restrict__ Wv, half_t* __restrict__ W16) {
  int i = blockIdx.x * 256 + threadIdx.x;
  const float* src = (i < 262144) ? Wq : ((i < 524288) ? Wk : Wv);
  int j = i & 262143;
  W16[i] = (half_t)src[j];
}

// ---------------- transpose x (B,D,L) f32 -> xT (B,L,D) f16 ----------------
// 64x64 tiles, float4 loads, half8 stores.
__global__ __launch_bounds__(256) void transpose_x(
    const float* __restrict__ x, half_t* __restrict__ xT) {
  __shared__ float tile[64][68];   // 68: 16B-aligned rows, bank shift 4
  int b = blockIdx.z;
  int d0 = blockIdx.y * 64;
  int l0 = blockIdx.x * 64;
  int t = threadIdx.x;
  int dy = t >> 4, lx = t & 15;
  const float* xp = x + ((size_t)(b * 512 + d0)) * 2048 + l0;
#pragma unroll
  for (int rr = 0; rr < 4; rr++) {
    float4 v = *(const float4*)(xp + (size_t)(rr * 16 + dy) * 2048 + lx * 4);
    *(float4*)&tile[rr * 16 + dy][lx * 4] = v;
  }
  __syncthreads();
  half_t* op = xT + ((size_t)(b * 2048 + l0)) * 512 + d0;
  int lr = t >> 2, c4 = t & 3;
#pragma unroll
  for (int cc = 0; cc < 2; cc++) {
    int ch = cc * 4 + c4;          // chunk of 8 d values
    half8v hv;
#pragma unroll
    for (int e = 0; e < 8; e++) hv[e] = (half_t)tile[ch * 8 + e][lr];
    *(half8v*)(op + (size_t)lr * 512 + ch * 8) = hv;
  }
}

// ---------------- per-h table builder (setup folded in) --------------------
__global__ __launch_bounds__(256) void s4d_tables(
    const float* __restrict__ log_dt, const float* __restrict__ A_real,
    const float* __restrict__ A_imag, const float* __restrict__ C_re,
    const float* __restrict__ C_im, const float* __restrict__ shC,
    half_t* __restrict__ Vt, half_t* __restrict__ Et, half_t* __restrict__ Tt,
    half_t* __restrict__ T1t, half_t* __restrict__ T2t,
    float* __restrict__ wt2) {
  __shared__ float aL[32], bL[32], wrL[32], wiL[32], crL[32], ciL[32];
  __shared__ float Kt[64], tapl[64];
  int h = blockIdx.x;
  int tid = threadIdx.x;
  if (tid < 64) { Kt[tid] = 0.f; tapl[tid] = shC[h * 64 + tid]; }
  if (tid < 32) {
    int n = tid, hn = h * 32 + n;
    float dt = expf(log_dt[h]);
    float Ar = -expf(A_real[hn]), Ai = A_imag[hn];
    float a = dt * Ar, b = dt * Ai;
    float ea = expf(a);
    float wr = ea * cosf(b), wi = ea * sinf(b);
    float Am2 = Ar * Ar + Ai * Ai;
    float zr = wr - 1.0f, zi = wi;
    float qr = (zr * Ar + zi * Ai) / Am2;
    float qi = (zi * Ar - zr * Ai) / Am2;
    aL[n] = a; bL[n] = b; wrL[n] = wr; wiL[n] = wi;
    crL[n] = C_re[hn] * qr - C_im[hn] * qi;
    ciL[n] = C_re[hn] * qi + C_im[hn] * qr;
    float e64 = expf(64.0f * a);
    wt2[h * 64 + 2 * n]     = e64 * cosf(64.0f * b);
    wt2[h * 64 + 2 * n + 1] = e64 * sinf(64.0f * b);
  }
  __syncthreads();
  size_t base = (size_t)h * 4096;
  {
    int r = tid >> 2;
    int nb = (tid & 3) * 8;
    float ksum = 0.f;
#pragma unroll
    for (int i = 0; i < 8; i++) {
      int n = nb + i;
      float a = aL[n], b = bL[n];
      float cr = crL[n], ci = ciL[n];
      float er = expf(a * (float)r);
      float w0r = er * cosf(b * (float)r), w0i = er * sinf(b * (float)r);
      ksum += 2.f * (cr * w0r - ci * w0i);
      float wr = wrL[n], wi = wiL[n];
      float w1r = w0r * wr - w0i * wi, w1i = w0r * wi + w0i * wr;
      Et[base + SW(r, 2 * n)]     = (half_t)(2.f * (cr * w1r - ci * w1i));
      Et[base + SW(r, 2 * n + 1)] = (half_t)(-2.f * (cr * w1i + ci * w1r));
      Vt[base + SW(2 * n, 63 - r)]     = (half_t)w0r;
      Vt[base + SW(2 * n + 1, 63 - r)] = (half_t)w0i;
    }
    atomicAdd(&Kt[r], ksum);
  }
  __syncthreads();
#pragma unroll
  for (int e = 0; e < 16; e++) {
    int idx = e * 256 + tid;
    int r = idx >> 6, t = idx & 63;
    int d = r - t;
    size_t a = base + SW(r, t);
    Tt[a]  = (d >= 0) ? (half_t)Kt[d] : (half_t)0.f;
    T1t[a] = (d >= 0) ? (half_t)tapl[d] : (half_t)0.f;
    T2t[a] = (d < 0) ? (half_t)tapl[64 + d] : (half_t)0.f;
  }
}

// ---------------- merged qkv GEMM (128x128, BK=64, LDS epilogue) -----------
__global__ __launch_bounds__(256) void gemm_qkv(
    const half_t* __restrict__ xT, const half_t* __restrict__ Wstk,
    const float* __restrict__ bq, const float* __restrict__ bk,
    const float* __restrict__ bv, half_t* __restrict__ outq,
    half_t* __restrict__ outk, half_t* __restrict__ outv) {
  __shared__ half_t smem[16384];   // As 8192 | Bs 8192; reused as C 128x128
  half_t* As = smem;
  half_t* Bs = smem + 8192;
  int flat = blockIdx.x;                         // 1536 = 8 xcd x 192
  int swz = (flat & 7) * 192 + (flat >> 3);      // XCD chunk swizzle
  int nt = swz / 12, mt = swz - nt * 12;
  int n0 = nt * 128, m0 = mt * 128;
  int tid = threadIdx.x;
  int lane = tid & 63, wid = tid >> 6;
  int wr = wid >> 1, wc = wid & 1;
  int lrow = lane & 15, lg = lane >> 4;
  int rsub = lane >> 3, ssub = lane & 7;
  int gslot = ssub ^ rsub;                       // inverse-swizzled source slot

  floatx4 acc[4][4];
#pragma unroll
  for (int i = 0; i < 4; i++)
#pragma unroll
    for (int j = 0; j < 4; j++) acc[i][j] = (floatx4){0.f, 0.f, 0.f, 0.f};

  const half_t* gA = Wstk + (size_t)(m0 + wid * 32 + rsub) * 512 + gslot * 8;
  const half_t* gB = xT + (size_t)(n0 + wid * 32 + rsub) * 512 + gslot * 8;

  for (int kk = 0; kk < 512; kk += 64) {
#pragma unroll
    for (int i = 0; i < 4; i++) {
      int c = wid * 4 + i;                       // 1KB chunk, rows c*8..c*8+7
      gload_lds16(gA + (size_t)i * 8 * 512 + kk, As + c * 512);
      gload_lds16(gB + (size_t)i * 8 * 512 + kk, Bs + c * 512);
    }
    __syncthreads();
#pragma unroll
    for (int h = 0; h < 2; h++) {
      half8v af[4], bf[4];
#pragma unroll
      for (int i = 0; i < 4; i++) {
        int r = wr * 64 + i * 16 + lrow;
        af[i] = *(const half8v*)(As + r * 64 + ((h * 4 + lg) ^ (r & 7)) * 8);
      }
#pragma unroll
      for (int j = 0; j < 4; j++) {
        int r = wc * 64 + j * 16 + lrow;
        bf[j] = *(const half8v*)(Bs + r * 64 + ((h * 4 + lg) ^ (r & 7)) * 8);
      }
#pragma unroll
      for (int i = 0; i < 4; i++)
#pragma unroll
        for (int j = 0; j < 4; j++)
          acc[i][j] = __builtin_amdgcn_mfma_f32_16x16x32_f16(af[i], bf[j],
                                                             acc[i][j], 0, 0, 0);
    }
    __syncthreads();
  }

  // ---- epilogue via LDS: frags -> swizzled C tile -> coalesced stores ----
  int z = m0 >> 9;                               // uniform per block
  const float* bias = (z == 0) ? bq : ((z == 1) ? bk : bv);
  half_t* smemC = smem;                          // 128 x 128 halfs, slot^=(d&15)
#pragma unroll
  for (int i = 0; i < 4; i++) {
    int dl = wr * 64 + i * 16 + 4 * lg;
    float4 b4 = *(const float4*)&bias[(m0 + dl) & 511];
#pragma unroll
    for (int j = 0; j < 4; j++) {
      int ll = wc * 64 + j * 16 + lrow;
#pragma unroll
      for (int reg = 0; reg < 4; reg++) {
        int d = dl + reg;
        float val = acc[i][j][reg] + ((const float*)&b4)[reg];
        smemC[d * 128 + (((ll >> 3) ^ (d & 15)) << 3) + (ll & 7)] = (half_t)val;
      }
    }
  }
  __syncthreads();
  {
    int t4 = tid >> 4, ch = tid & 15;
    int b = n0 >> 11, l0 = n0 & 2047;
    half_t* outp = (z == 0) ? outq : ((z == 1) ? outk : outv);
#pragma unroll
    for (int rep = 0; rep < 8; rep++) {
      int d = rep * 16 + t4;
      half8v v = *(const half8v*)(smemC + d * 128 + ((ch ^ (d & 15)) << 3));
      size_t rowb = ((size_t)(b * 512 + ((m0 + d) & 511))) * 2048;
      if (z == 0) {
        *(half8v*)(outp + rowb + l0 + ch * 8) = v;       // q: linear
      } else {                                            // k,v: swizzled image
        int j = (l0 >> 6) + (ch >> 3);
        int s = ch & 7;
        *(half8v*)(outp + rowb + j * 64 + ((s ^ (j & 7)) << 3)) = v;
      }
    }
  }
}

// ---------------- fused Shift + S4D + final q-multiply ---------------------
// One block per (b,h); wave w: mi = w&1 (chunk-tile), ri in {w>>1, w>>1+2}.
__global__ __launch_bounds__(256) void s4d_main(
    const half_t* __restrict__ kimg, const half_t* __restrict__ vimg,
    const half_t* __restrict__ T1t, const half_t* __restrict__ T2t,
    const half_t* __restrict__ Vt, const half_t* __restrict__ Et,
    const half_t* __restrict__ Tt, const float* __restrict__ wt2,
    const float* __restrict__ shD, const float* __restrict__ s4D,
    const half_t* __restrict__ qbuf, float* __restrict__ outp) {
  __shared__ half_t kl[33 * 64];   // row 0 zeros; row 1+j = k chunk j
  __shared__ half_t vg[32 * 64];   // v, later G~ (f16)
  __shared__ half_t uh[32 * 64];   // u = v * shift(k)
  __shared__ half_t tab0[64 * 64]; // T1 -> E
  __shared__ half_t tab1[64 * 64]; // T2 -> T
  __shared__ half_t tab2[64 * 64]; // V
  __shared__ float SG[32 * 66];    // scan states, then flat y[2048]
  int bh = blockIdx.x;
  int h = bh & 511;
  int tid = threadIdx.x;
  int lane = tid & 63, wid = tid >> 6;
  int lrow = lane & 15, lg = lane >> 4;
  int mi = wid & 1;
  int ri0 = wid >> 1;

  // ---- stage k, v, T1, T2, V via gload_lds (8 per wave) ----
  {
    const half_t* kp = kimg + (size_t)bh * 2048;
    const half_t* vp = vimg + (size_t)bh * 2048;
    size_t tb = (size_t)h * 4096;
    gload_lds16(kp + wid * 512 + lane * 8, kl + 64 + wid * 512);
    gload_lds16(vp + wid * 512 + lane * 8, vg + wid * 512);
#pragma unroll
    for (int i = 0; i < 2; i++) {
      int c = wid * 2 + i;
      gload_lds16(T1t + tb + c * 512 + lane * 8, tab0 + c * 512);
      gload_lds16(T2t + tb + c * 512 + lane * 8, tab1 + c * 512);
      gload_lds16(Vt + tb + c * 512 + lane * 8, tab2 + c * 512);
    }
  }
  if (tid < 8) {
    half8v zz = {(_Float16)0, (_Float16)0, (_Float16)0, (_Float16)0,
                 (_Float16)0, (_Float16)0, (_Float16)0, (_Float16)0};
    *(half8v*)(kl + tid * 8) = zz;
  }
  float sDsh = shD[h];
  float sD4 = s4D[h];
  __syncthreads();

#define LDF(base, r, ks, key) \
  (*(const half8v*)((base) + (r) * 64 + (((ks) * 4 + lg) ^ (key)) * 8))

  floatx4 acc[2];
  // ---- shift: shift[j][r] = k_j @ T1' + k_{j-1} @ T2' ----
  acc[0] = (floatx4){0.f, 0.f, 0.f, 0.f};
  acc[1] = (floatx4){0.f, 0.f, 0.f, 0.f};
  {
    int jA = mi * 16 + lrow;
    int key1 = lrow & 7, key2 = (lrow + 7) & 7;
#pragma unroll
    for (int ks = 0; ks < 2; ks++) {
      half8v a1 = LDF(kl, 1 + jA, ks, key1);
      half8v a2 = LDF(kl, jA, ks, key2);
#pragma unroll
      for (int tt = 0; tt < 2; tt++) {
        int rb = (ri0 + tt * 2) * 16 + lrow;
        half8v b1 = LDF(tab0, rb, ks, lrow & 7);
        half8v b2 = LDF(tab1, rb, ks, lrow & 7);
        acc[tt] = __builtin_amdgcn_mfma_f32_16x16x32_f16(a1, b1, acc[tt], 0, 0, 0);
        acc[tt] = __builtin_amdgcn_mfma_f32_16x16x32_f16(a2, b2, acc[tt], 0, 0, 0);
      }
    }
  }
  // u = v * (shift + shD*k)
#pragma unroll
  for (int tt = 0; tt < 2; tt++) {
#pragma unroll
    for (int reg = 0; reg < 4; reg++) {
      int j = mi * 16 + 4 * lg + reg;
      int r = (ri0 + tt * 2) * 16 + lrow;
      int cph = (((r >> 3) ^ (j & 7)) << 3) + (r & 7);
      float kvv = (float)kl[(1 + j) * 64 + cph];
      float vvv = (float)vg[j * 64 + cph];
      uh[j * 64 + cph] = (half_t)(vvv * (acc[tt][reg] + sDsh * kvv));
    }
  }
  __syncthreads();

  // ---- issue E,T stage (overlaps with S phase) ----
  {
    size_t tb = (size_t)h * 4096;
#pragma unroll
    for (int i = 0; i < 2; i++) {
      int c = wid * 2 + i;
      gload_lds16(Et + tb + c * 512 + lane * 8, tab0 + c * 512);
      gload_lds16(Tt + tb + c * 512 + lane * 8, tab1 + c * 512);
    }
  }

  // ---- S phase: S[j][m] = u_j @ V' ----
  acc[0] = (floatx4){0.f, 0.f, 0.f, 0.f};
  acc[1] = (floatx4){0.f, 0.f, 0.f, 0.f};
#pragma unroll
  for (int ks = 0; ks < 2; ks++) {
    half8v a = LDF(uh, mi * 16 + lrow, ks, lrow & 7);
#pragma unroll
    for (int tt = 0; tt < 2; tt++) {
      int rb = (ri0 + tt * 2) * 16 + lrow;
      half8v b = LDF(tab2, rb, ks, lrow & 7);
      acc[tt] = __builtin_amdgcn_mfma_f32_16x16x32_f16(a, b, acc[tt], 0, 0, 0);
    }
  }
#pragma unroll
  for (int tt = 0; tt < 2; tt++) {
    int ri = ri0 + tt * 2;
#pragma unroll
    for (int reg = 0; reg < 4; reg++) {
      int j = mi * 16 + 4 * lg + reg;
      SG[j * 66 + ri * 16 + lrow] = acc[tt][reg];
    }
  }
  __syncthreads();   // drains E,T stage too

  // ---- scan over chunks (thread n), SG[j] <- G_{j-1} ----
  if (tid < 32) {
    int n = tid;
    float wTr = wt2[h * 64 + 2 * n], wTi = wt2[h * 64 + 2 * n + 1];
    float gr = 0.f, gi = 0.f;
    for (int j = 0; j < 32; j++) {
      float tr = SG[j * 66 + 2 * n], ti = SG[j * 66 + 2 * n + 1];
      SG[j * 66 + 2 * n] = gr; SG[j * 66 + 2 * n + 1] = gi;
      float nr = wTr * gr - wTi * gi + tr;
      gi = wTr * gi + wTi * gr + ti;
      gr = nr;
    }
  }
  __syncthreads();

  // ---- convert G (f32) -> f16 into vg (swizzled) ----
  {
    int j = tid >> 3, s = tid & 7;
    half8v g;
#pragma unroll
    for (int i = 0; i < 8; i++) g[i] = (half_t)SG[j * 66 + s * 8 + i];
    *(half8v*)(vg + j * 64 + (s ^ (j & 7)) * 8) = g;
  }
  __syncthreads();

  // ---- Y: Y[j][r] = G~_j @ E' + u_j @ T' ; y -> LDS (flat) ----
  acc[0] = (floatx4){0.f, 0.f, 0.f, 0.f};
  acc[1] = (floatx4){0.f, 0.f, 0.f, 0.f};
#pragma unroll
  for (int ks = 0; ks < 2; ks++) {
    half8v ag = LDF(vg, mi * 16 + lrow, ks, lrow & 7);
    half8v au = LDF(uh, mi * 16 + lrow, ks, lrow & 7);
#pragma unroll
    for (int tt = 0; tt < 2; tt++) {
      int rb = (ri0 + tt * 2) * 16 + lrow;
      half8v be = LDF(tab0, rb, ks, lrow & 7);
      half8v bt = LDF(tab1, rb, ks, lrow & 7);
      acc[tt] = __builtin_amdgcn_mfma_f32_16x16x32_f16(ag, be, acc[tt], 0, 0, 0);
      acc[tt] = __builtin_amdgcn_mfma_f32_16x16x32_f16(au, bt, acc[tt], 0, 0, 0);
    }
  }
#pragma unroll
  for (int tt = 0; tt < 2; tt++) {
#pragma unroll
    for (int reg = 0; reg < 4; reg++) {
      int j = mi * 16 + 4 * lg + reg;
      int r = (ri0 + tt * 2) * 16 + lrow;
      int cph = (((r >> 3) ^ (j & 7)) << 3) + (r & 7);
      SG[j * 64 + r] = acc[tt][reg] + sD4 * (float)uh[j * 64 + cph];
    }
  }
  __syncthreads();

  // ---- final coalesced pass: out = q * y ----
  {
    const half_t* qp = qbuf + (size_t)bh * 2048;
    float* op = outp + (size_t)bh * 2048;
    half8v qv = *(const half8v*)(qp + tid * 8);
    float4 o0, o1;
    o0.x = (float)qv[0] * SG[tid * 8 + 0];
    o0.y = (float)qv[1] * SG[tid * 8 + 1];
    o0.z = (float)qv[2] * SG[tid * 8 + 2];
    o0.w = (float)qv[3] * SG[tid * 8 + 3];
    o1.x = (float)qv[4] * SG[tid * 8 + 4];
    o1.y = (float)qv[5] * SG[tid * 8 + 5];
    o1.z = (float)qv[6] * SG[tid * 8 + 6];
    o1.w = (float)qv[7] * SG[tid * 8 + 7];
    *(float4*)(op + tid * 8) = o0;
    *(float4*)(op + tid * 8 + 4) = o1;
  }
#undef LDF
}

// ---------------------------------------------------------------------------
extern "C" void kernel_launch(void* const* d_in, const int* in_sizes, int n_in,
                              void* d_out, int out_size, void* d_ws, size_t ws_size,
                              hipStream_t stream) {
  const float* x      = (const float*)d_in[0];
  const float* Wq     = (const float*)d_in[1];
  const float* bq     = (const float*)d_in[2];
  const float* Wk     = (const float*)d_in[3];
  const float* bk     = (const float*)d_in[4];
  const float* Wv     = (const float*)d_in[5];
  const float* bv     = (const float*)d_in[6];
  const float* shC    = (const float*)d_in[7];
  const float* shD    = (const float*)d_in[8];
  const float* log_dt = (const float*)d_in[9];
  const float* A_real = (const float*)d_in[10];
  const float* A_imag = (const float*)d_in[11];
  const float* C_re   = (const float*)d_in[12];
  const float* C_im   = (const float*)d_in[13];
  const float* s4D    = (const float*)d_in[14];
  float* out = (float*)d_out;
  half_t* wsh = (half_t*)d_ws;

  half_t* qbuf = wsh;                         // 8388608 halfs (linear)
  half_t* kbuf = wsh + 8388608;               // 8388608 (swizzled image)
  half_t* vbuf = wsh + 16777216;              // 8388608 (swizzled image)
  half_t* xT16 = wsh + 25165824;              // 8388608
  half_t* W16  = wsh + 33554432;              // 786432
  half_t* Vt   = wsh + 34340864;              // 2097152 (swizzled image)
  half_t* Et   = wsh + 36438016;              // 2097152
  half_t* Tt   = wsh + 38535168;              // 2097152
  half_t* T1t  = wsh + 40632320;              // 2097152
  half_t* T2t  = wsh + 42729472;              // 2097152
  float*  wt2  = (float*)(wsh + 44826624);    // 32768 f32

  convert_w<<<3072, 256, 0, stream>>>(Wq, Wk, Wv, W16);
  transpose_x<<<dim3(32, 8, 8), 256, 0, stream>>>(x, xT16);
  s4d_tables<<<512, 256, 0, stream>>>(log_dt, A_real, A_imag, C_re, C_im, shC,
                                      Vt, Et, Tt, T1t, T2t, wt2);
  gemm_qkv<<<dim3(1536), 256, 0, stream>>>(xT16, W16, bq, bk, bv,
                                           qbuf, kbuf, vbuf);
  s4d_main<<<4096, 256, 0, stream>>>(kbuf, vbuf, T1t, T2t, Vt, Et, Tt,
                                     wt2, shD, s4D, qbuf, out);
}